// Round 1
// baseline (404.156 us; speedup 1.0000x reference)
//
#include <hip/hip_runtime.h>
#include <stdint.h>

#define WB 8
#define WC 32
#define WU 32
#define WK 5
#define WN 256
#define NN 65536     // 256*256
#define KC 160       // WK*WC = contraction size of stage 2, also l*u size
#define KQ 1280      // WK*WN = contraction size of stage 3

typedef __attribute__((ext_vector_type(8))) short bf8;   // 8 x bf16 (4 VGPRs)
typedef __attribute__((ext_vector_type(4))) float f4;    // MFMA accumulator

__device__ __forceinline__ unsigned short f2b(float f) {
    union { float f; uint32_t u; } v; v.f = f;
    uint32_t u = v.u;
    return (unsigned short)((u + 0x7FFFu + ((u >> 16) & 1u)) >> 16);  // RNE
}

// ---------------------------------------------------------------------------
// P0: small repacks (bf16): c1T[k][m][p], c2T[n][l*256+q], Wt[(l,u)][(k,i)]
// ---------------------------------------------------------------------------
__global__ void prep_small(const float* __restrict__ cheb1,
                           const float* __restrict__ cheb2,
                           const float* __restrict__ coefs,
                           unsigned short* __restrict__ c1T,
                           unsigned short* __restrict__ c2T,
                           unsigned short* __restrict__ Wt) {
    int idx = blockIdx.x * 256 + threadIdx.x;
    if (idx < WK * NN) {            // c1T[k][m][p] = cheb1[k][p][m]
        int k = idx / NN, r = idx % NN, m = r / WN, p = r % WN;
        c1T[idx] = f2b(cheb1[(k * WN + p) * WN + m]);
    }
    if (idx < WN * KQ) {            // c2T[n][lq] = cheb2[lq][n]
        int n = idx / KQ, r = idx % KQ;
        c2T[idx] = f2b(cheb2[r * WN + n]);
    }
    if (idx < KC * KC) {            // Wt[l*32+u][k*32+i] = coefs[k][l][i][u]
        int lu = idx / KC, ki = idx % KC;
        int l = lu >> 5, u = lu & 31, k = ki >> 5, i = ki & 31;
        Wt[idx] = f2b(coefs[((k * WK + l) * WC + i) * WU + u]);
    }
}

// ---------------------------------------------------------------------------
// P1: xT[b][i][q][p] (bf16) = x[b][i][p][q]   (64x64 LDS tile transpose)
// ---------------------------------------------------------------------------
__global__ void prep_x(const float* __restrict__ x, unsigned short* __restrict__ xT) {
    __shared__ unsigned short tile[64][72];
    int bi = blockIdx.z;
    int p0 = blockIdx.y * 64, q0 = blockIdx.x * 64;
    const float* src = x + (size_t)bi * NN;
    unsigned short* dst = xT + (size_t)bi * NN;
    int t = threadIdx.x;
    int c4 = (t & 15) * 4, r0 = t >> 4;
    for (int it = 0; it < 4; ++it) {
        int r = r0 + it * 16;
        float4 v = *reinterpret_cast<const float4*>(&src[(size_t)(p0 + r) * WN + q0 + c4]);
        tile[r][c4 + 0] = f2b(v.x); tile[r][c4 + 1] = f2b(v.y);
        tile[r][c4 + 2] = f2b(v.z); tile[r][c4 + 3] = f2b(v.w);
    }
    __syncthreads();
    for (int it = 0; it < 4; ++it) {
        int q = r0 + it * 16;
        ushort4 o;
        o.x = tile[c4 + 0][q]; o.y = tile[c4 + 1][q];
        o.z = tile[c4 + 2][q]; o.w = tile[c4 + 3][q];
        *reinterpret_cast<ushort4*>(&dst[(size_t)(q0 + q) * WN + p0 + c4]) = o;
    }
}

// ---------------------------------------------------------------------------
// G1: a[bl][k*32+i][m][q] = sum_p cheb1[k,p,m] * x[b,i,p,q]
//     batched GEMM, tiles 128x128, BK=32, 4 waves of 64x64
// ---------------------------------------------------------------------------
__global__ __launch_bounds__(256) void g1(const unsigned short* __restrict__ c1T,
                                          const unsigned short* __restrict__ xT,
                                          unsigned short* __restrict__ a, int b_base) {
    __shared__ unsigned short As[128][40];   // [m][p], pitch 80B (16B-aligned rows)
    __shared__ unsigned short Bs[128][40];   // [q][p]
    int z = blockIdx.z;
    int bl = z / KC, ki = z % KC, k = ki >> 5, i = ki & 31;
    int m0 = blockIdx.y * 128, q0 = blockIdx.x * 128;
    int b = b_base + bl;
    const unsigned short* Asrc = c1T + (size_t)k * NN;             // [m][p]
    const unsigned short* Bsrc = xT + (size_t)(b * WC + i) * NN;   // [q][p]
    unsigned short* Out = a + ((size_t)bl * KC + ki) * NN;

    int t = threadIdx.x;
    int w = t >> 6, l = t & 63;
    int wm = (w & 1) * 64, wn = (w >> 1) * 64;
    int lr = l & 15, g = (l >> 4) * 8;

    f4 acc[4][4];
    for (int mf = 0; mf < 4; ++mf) for (int nf = 0; nf < 4; ++nf) acc[mf][nf] = (f4)(0.0f);

    for (int p0 = 0; p0 < WN; p0 += 32) {
        __syncthreads();
        for (int s = 0; s < 2; ++s) {
            int idx = t + s * 256;
            int row = idx >> 2, kc = (idx & 3) * 8;
            *reinterpret_cast<bf8*>(&As[row][kc]) =
                *reinterpret_cast<const bf8*>(&Asrc[(size_t)(m0 + row) * WN + p0 + kc]);
            *reinterpret_cast<bf8*>(&Bs[row][kc]) =
                *reinterpret_cast<const bf8*>(&Bsrc[(size_t)(q0 + row) * WN + p0 + kc]);
        }
        __syncthreads();
        bf8 af[4], bfr[4];
        for (int mf = 0; mf < 4; ++mf)
            af[mf] = *reinterpret_cast<const bf8*>(&As[wm + mf * 16 + lr][g]);
        for (int nf = 0; nf < 4; ++nf)
            bfr[nf] = *reinterpret_cast<const bf8*>(&Bs[wn + nf * 16 + lr][g]);
        for (int mf = 0; mf < 4; ++mf)
            for (int nf = 0; nf < 4; ++nf)
                acc[mf][nf] = __builtin_amdgcn_mfma_f32_16x16x32_bf16(af[mf], bfr[nf], acc[mf][nf], 0, 0, 0);
    }
    int lg = (l >> 4) * 4;
    for (int mf = 0; mf < 4; ++mf)
        for (int nf = 0; nf < 4; ++nf)
            for (int j = 0; j < 4; ++j) {
                int m = m0 + wm + mf * 16 + lg + j;   // D row
                int q = q0 + wn + nf * 16 + lr;       // D col
                Out[(size_t)m * WN + q] = f2b(acc[mf][nf][j]);
            }
}

// ---------------------------------------------------------------------------
// T3: aT[bl][(m,q)][(k,i)] = a[bl][(k,i)][(m,q)]   (LDS transpose, 160x64 tiles)
// ---------------------------------------------------------------------------
__global__ void t3(const unsigned short* __restrict__ a, unsigned short* __restrict__ aT) {
    __shared__ unsigned short tile[160][72];
    int bl = blockIdx.z, m = blockIdx.y, q0 = blockIdx.x * 64;
    const unsigned short* src = a + (size_t)bl * KC * NN + (size_t)m * WN + q0;
    unsigned short* dst = aT + ((size_t)bl * NN + (size_t)m * WN + q0) * KC;
    int t = threadIdx.x;
    for (int s = 0; s < 10; ++s) {
        int idx = t + s * 256;
        int row = idx / 16, c4 = (idx % 16) * 4;
        *reinterpret_cast<ushort4*>(&tile[row][c4]) =
            *reinterpret_cast<const ushort4*>(&src[(size_t)row * NN + c4]);
    }
    __syncthreads();
    for (int s = 0; s < 10; ++s) {
        int idx = t + s * 256;
        int q = idx / 40, kc = (idx % 40) * 4;
        ushort4 o;
        o.x = tile[kc + 0][q]; o.y = tile[kc + 1][q];
        o.z = tile[kc + 2][q]; o.w = tile[kc + 3][q];
        *reinterpret_cast<ushort4*>(&dst[(size_t)q * KC + kc]) = o;
    }
}

// ---------------------------------------------------------------------------
// G2: c[bl][(l,u)][(m,q)] = Wt[160x160] @ aT^T  — M=160, N=65536, K=160
//     Wt resident in LDS; 4 waves each own 160x32 of the 160x128 tile
// ---------------------------------------------------------------------------
__global__ __launch_bounds__(256) void g2(const unsigned short* __restrict__ Wt,
                                          const unsigned short* __restrict__ aT,
                                          unsigned short* __restrict__ c) {
    __shared__ unsigned short As[160][168];  // whole Wt, pitch 336B
    __shared__ unsigned short Bs[128][40];
    int bl = blockIdx.y;
    int n0 = blockIdx.x * 128;                       // (m,q) pixel offset
    const unsigned short* Bsrc = aT + ((size_t)bl * NN + n0) * KC;
    unsigned short* Out = c + (size_t)bl * KC * NN;
    int t = threadIdx.x;
    for (int s = 0; s < 13; ++s) {
        int idx = t + s * 256;
        if (idx < 3200) {
            int row = idx / 20, kc = (idx % 20) * 8;
            *reinterpret_cast<bf8*>(&As[row][kc]) =
                *reinterpret_cast<const bf8*>(&Wt[(size_t)row * KC + kc]);
        }
    }
    int w = t >> 6, l = t & 63;
    int wn = w * 32, lr = l & 15, g = (l >> 4) * 8;
    f4 acc[10][2];
    for (int mf = 0; mf < 10; ++mf) { acc[mf][0] = (f4)(0.0f); acc[mf][1] = (f4)(0.0f); }

    for (int k0 = 0; k0 < KC; k0 += 32) {
        __syncthreads();
        for (int s = 0; s < 2; ++s) {
            int idx = t + s * 256;
            int row = idx >> 2, kc = (idx & 3) * 8;
            *reinterpret_cast<bf8*>(&Bs[row][kc]) =
                *reinterpret_cast<const bf8*>(&Bsrc[(size_t)row * KC + k0 + kc]);
        }
        __syncthreads();
        bf8 b0 = *reinterpret_cast<const bf8*>(&Bs[wn + lr][g]);
        bf8 b1 = *reinterpret_cast<const bf8*>(&Bs[wn + 16 + lr][g]);
        for (int mf = 0; mf < 10; ++mf) {
            bf8 af = *reinterpret_cast<const bf8*>(&As[mf * 16 + lr][k0 + g]);
            acc[mf][0] = __builtin_amdgcn_mfma_f32_16x16x32_bf16(af, b0, acc[mf][0], 0, 0, 0);
            acc[mf][1] = __builtin_amdgcn_mfma_f32_16x16x32_bf16(af, b1, acc[mf][1], 0, 0, 0);
        }
    }
    int lg = (l >> 4) * 4;
    for (int mf = 0; mf < 10; ++mf)
        for (int nf = 0; nf < 2; ++nf)
            for (int j = 0; j < 4; ++j) {
                int row = mf * 16 + lg + j;          // (l,u)
                int col = n0 + wn + nf * 16 + lr;    // (m,q)
                Out[(size_t)row * NN + col] = f2b(acc[mf][nf][j]);
            }
}

// ---------------------------------------------------------------------------
// G3: out[b][u][m][n] = sum_{l,q} c[bl][l][u][m][q] * cheb2[l][q][n]
//     per-b GEMM M=8192 (u,m), N=256, K=1280; tiles 128x128
// ---------------------------------------------------------------------------
__global__ __launch_bounds__(256) void g3(const unsigned short* __restrict__ c,
                                          const unsigned short* __restrict__ c2T,
                                          float* __restrict__ out, int b_base) {
    __shared__ unsigned short As[128][40];
    __shared__ unsigned short Bs[128][40];
    int bl = blockIdx.z;
    int n0 = blockIdx.x * 128, r0 = blockIdx.y * 128;   // r = u*256+m
    const unsigned short* Csrc = c + (size_t)bl * KC * NN;
    int t = threadIdx.x;
    int w = t >> 6, l = t & 63;
    int wm = (w & 1) * 64, wn = (w >> 1) * 64;
    int lr = l & 15, g = (l >> 4) * 8;
    f4 acc[4][4];
    for (int mf = 0; mf < 4; ++mf) for (int nf = 0; nf < 4; ++nf) acc[mf][nf] = (f4)(0.0f);

    for (int k0 = 0; k0 < KQ; k0 += 32) {
        int lq_l = k0 >> 8, qq = k0 & 255;   // k = l*256 + q, q-chunk contiguous
        __syncthreads();
        for (int s = 0; s < 2; ++s) {
            int idx = t + s * 256;
            int row = idx >> 2, kc = (idx & 3) * 8;
            int R = r0 + row, u = R >> 8, m = R & 255;
            *reinterpret_cast<bf8*>(&As[row][kc]) =
                *reinterpret_cast<const bf8*>(&Csrc[((size_t)(lq_l * WU + u) * WN + m) * WN + qq + kc]);
            *reinterpret_cast<bf8*>(&Bs[row][kc]) =
                *reinterpret_cast<const bf8*>(&c2T[(size_t)(n0 + row) * KQ + k0 + kc]);
        }
        __syncthreads();
        bf8 af[4], bfr[4];
        for (int mf = 0; mf < 4; ++mf)
            af[mf] = *reinterpret_cast<const bf8*>(&As[wm + mf * 16 + lr][g]);
        for (int nf = 0; nf < 4; ++nf)
            bfr[nf] = *reinterpret_cast<const bf8*>(&Bs[wn + nf * 16 + lr][g]);
        for (int mf = 0; mf < 4; ++mf)
            for (int nf = 0; nf < 4; ++nf)
                acc[mf][nf] = __builtin_amdgcn_mfma_f32_16x16x32_bf16(af[mf], bfr[nf], acc[mf][nf], 0, 0, 0);
    }
    int lg = (l >> 4) * 4;
    int b = b_base + bl;
    for (int mf = 0; mf < 4; ++mf)
        for (int nf = 0; nf < 4; ++nf)
            for (int j = 0; j < 4; ++j) {
                int R = r0 + wm + mf * 16 + lg + j;   // u*256+m
                int n = n0 + wn + nf * 16 + lr;
                int u = R >> 8, m = R & 255;
                out[((size_t)(b * WU + u) * WN + m) * WN + n] = acc[mf][nf][j];
            }
}

// ---------------------------------------------------------------------------
extern "C" void kernel_launch(void* const* d_in, const int* in_sizes, int n_in,
                              void* d_out, int out_size, void* d_ws, size_t ws_size,
                              hipStream_t stream) {
    const float* x     = (const float*)d_in[0];
    const float* cheb1 = (const float*)d_in[1];
    const float* cheb2 = (const float*)d_in[2];
    const float* coefs = (const float*)d_in[3];
    float* out = (float*)d_out;
    unsigned short* ws = (unsigned short*)d_ws;

    size_t off = 0;
    unsigned short* xT  = ws + off; off += (size_t)WB * WC * NN;   // 16.7M elems
    unsigned short* c1T = ws + off; off += (size_t)WK * NN;
    unsigned short* c2T = ws + off; off += (size_t)WN * KQ;
    unsigned short* Wt  = ws + off; off += (size_t)KC * KC;
    size_t fixed_elems = off;

    // per-batch chunk: a, aT, c each KC*NN bf16 elems
    size_t per_b = 3ull * KC * NN;
    size_t avail_elems = ws_size / 2 > fixed_elems ? ws_size / 2 - fixed_elems : 0;
    int nb = (int)(avail_elems / per_b);
    if (nb < 1) nb = 1;
    if (nb > WB) nb = WB;

    unsigned short* a_  = ws + fixed_elems;
    unsigned short* aT_ = a_  + (size_t)nb * KC * NN;
    unsigned short* c_  = aT_ + (size_t)nb * KC * NN;

    prep_small<<<1280, 256, 0, stream>>>(cheb1, cheb2, coefs, c1T, c2T, Wt);
    prep_x<<<dim3(4, 4, WB * WC), 256, 0, stream>>>(x, xT);

    for (int b0 = 0; b0 < WB; b0 += nb) {
        int cur = (WB - b0 < nb) ? (WB - b0) : nb;
        g1<<<dim3(2, 2, cur * KC), 256, 0, stream>>>(c1T, xT, a_, b0);
        t3<<<dim3(4, 256, cur), 256, 0, stream>>>(a_, aT_);
        g2<<<dim3(512, cur), 256, 0, stream>>>(Wt, aT_, c_);
        g3<<<dim3(2, 64, cur), 256, 0, stream>>>(c_, c2T, out, b0);
    }
}

// Round 2
// 326.577 us; speedup vs baseline: 1.2375x; 1.2375x over previous
//
#include <hip/hip_runtime.h>
#include <stdint.h>

#define WB 8
#define WC 32
#define WU 32
#define WK 5
#define WN 256
#define NN 65536     // 256*256
#define KC 160       // WK*WC
#define KQ 1280      // WK*WN

typedef __attribute__((ext_vector_type(8))) short bf8;     // 8 x bf16
typedef __attribute__((ext_vector_type(4))) short s4v;     // 4 x bf16
typedef __attribute__((ext_vector_type(8))) unsigned short us8;
typedef __attribute__((ext_vector_type(4))) float f4;

__device__ __forceinline__ unsigned short f2b(float f) {
    union { float f; uint32_t u; } v; v.f = f;
    uint32_t u = v.u;
    return (unsigned short)((u + 0x7FFFu + ((u >> 16) & 1u)) >> 16);  // RNE
}

// async global->LDS, 16B per lane; lds base must be wave-uniform (m97 pattern)
__device__ __forceinline__ void gload16(const unsigned short* g, unsigned short* l) {
    __builtin_amdgcn_global_load_lds(
        (const __attribute__((address_space(1))) unsigned int*)g,
        (__attribute__((address_space(3))) unsigned int*)l, 16, 0, 0);
}

// ---------------------------------------------------------------------------
// P0: repacks (bf16): c1T[k][m][p], c2T[n][l*256+q], Wt[(l,u)][(k,i)]
// ---------------------------------------------------------------------------
__global__ void prep_small(const float* __restrict__ cheb1,
                           const float* __restrict__ cheb2,
                           const float* __restrict__ coefs,
                           unsigned short* __restrict__ c1T,
                           unsigned short* __restrict__ c2T,
                           unsigned short* __restrict__ Wt) {
    int idx = blockIdx.x * 256 + threadIdx.x;
    if (idx < WK * NN) {            // c1T[k][m][p] = cheb1[k][p][m]
        int k = idx / NN, r = idx % NN, m = r / WN, p = r % WN;
        c1T[idx] = f2b(cheb1[(k * WN + p) * WN + m]);
    }
    if (idx < WN * KQ) {            // c2T[n][lq] = cheb2[lq][n]
        int n = idx / KQ, r = idx % KQ;
        c2T[idx] = f2b(cheb2[r * WN + n]);
    }
    if (idx < KC * KC) {            // Wt[l*32+u][k*32+i] = coefs[k][l][i][u]
        int lu = idx / KC, ki = idx % KC;
        int l = lu >> 5, u = lu & 31, k = ki >> 5, i = ki & 31;
        Wt[idx] = f2b(coefs[((k * WK + l) * WC + i) * WU + u]);
    }
}

// ---------------------------------------------------------------------------
// P1: xT[b][i][q][p] (bf16) = x[b][i][p][q]
// ---------------------------------------------------------------------------
__global__ void prep_x(const float* __restrict__ x, unsigned short* __restrict__ xT) {
    __shared__ unsigned short tile[64][72];
    int bi = blockIdx.z;
    int p0 = blockIdx.y * 64, q0 = blockIdx.x * 64;
    const float* src = x + (size_t)bi * NN;
    unsigned short* dst = xT + (size_t)bi * NN;
    int t = threadIdx.x;
    int c4 = (t & 15) * 4, r0 = t >> 4;
    for (int it = 0; it < 4; ++it) {
        int r = r0 + it * 16;
        float4 v = *reinterpret_cast<const float4*>(&src[(size_t)(p0 + r) * WN + q0 + c4]);
        tile[r][c4 + 0] = f2b(v.x); tile[r][c4 + 1] = f2b(v.y);
        tile[r][c4 + 2] = f2b(v.z); tile[r][c4 + 3] = f2b(v.w);
    }
    __syncthreads();
    for (int it = 0; it < 4; ++it) {
        int q = r0 + it * 16;
        ushort4 o;
        o.x = tile[c4 + 0][q]; o.y = tile[c4 + 1][q];
        o.z = tile[c4 + 2][q]; o.w = tile[c4 + 3][q];
        *reinterpret_cast<ushort4*>(&dst[(size_t)(q0 + q) * WN + p0 + c4]) = o;
    }
}

// ---------------------------------------------------------------------------
// G1: per (b,i): a[(k*32+i)][m][q] = sum_p c1T[(k,m)][p] * xT[b,i][q][p]
//     M=1280 rows (k,m), N=256 q, K=256. 128x128 tile BK=64, global_load_lds,
//     linear LDS + both-sides XOR swizzle (col16 ^= row&7).
// ---------------------------------------------------------------------------
__global__ __launch_bounds__(256, 3) void g1(const unsigned short* __restrict__ c1T,
                                             const unsigned short* __restrict__ xT,
                                             unsigned short* __restrict__ a, int b_base) {
    __shared__ unsigned short As[128 * 64];
    __shared__ unsigned short Bs[128 * 64];
    int z = blockIdx.z;
    int bl = z >> 5, i = z & 31;
    int row0 = blockIdx.y * 128;            // (k,m) row base
    int q0 = blockIdx.x * 128;
    int b = b_base + bl;
    const unsigned short* Asrc = c1T;                              // pitch 256
    const unsigned short* Bsrc = xT + (size_t)(b * WC + i) * NN;   // pitch 256
    unsigned short* Out = a + (size_t)bl * KC * NN;

    int t = threadIdx.x;
    int w = t >> 6, l = t & 63;
    int wm = (w & 1) * 64, wn = (w >> 1) * 64;
    int lr = l & 15, hi = l >> 4;
    int srow = l >> 3;                       // 0..7 within 8-row chunk
    int scol = ((l & 7) ^ srow) * 8;         // pre-swizzled source col (elems)

    f4 acc[4][4];
    for (int mf = 0; mf < 4; ++mf) for (int nf = 0; nf < 4; ++nf) acc[mf][nf] = (f4)(0.0f);

    for (int p0 = 0; p0 < 256; p0 += 64) {
        __syncthreads();
        for (int it = 0; it < 4; ++it) {
            int chunk = it * 4 + w;
            int row = chunk * 8 + srow;
            gload16(&Asrc[(size_t)(row0 + row) * 256 + p0 + scol], &As[chunk * 512]);
            gload16(&Bsrc[(size_t)(q0 + row) * 256 + p0 + scol], &Bs[chunk * 512]);
        }
        __syncthreads();
        bf8 af[2][4], bfr[2][4];
        for (int kk = 0; kk < 2; ++kk)
            for (int mf = 0; mf < 4; ++mf) {
                int r = wm + mf * 16 + lr;
                af[kk][mf] = *(const bf8*)&As[r * 64 + (((kk * 4 + hi) ^ (r & 7)) * 8)];
                int rb = wn + mf * 16 + lr;
                bfr[kk][mf] = *(const bf8*)&Bs[rb * 64 + (((kk * 4 + hi) ^ (rb & 7)) * 8)];
            }
        for (int kk = 0; kk < 2; ++kk)
            for (int mf = 0; mf < 4; ++mf)
                for (int nf = 0; nf < 4; ++nf)
                    acc[mf][nf] = __builtin_amdgcn_mfma_f32_16x16x32_bf16(af[kk][mf], bfr[kk][nf], acc[mf][nf], 0, 0, 0);
    }
    for (int mf = 0; mf < 4; ++mf)
        for (int nf = 0; nf < 4; ++nf)
            for (int j = 0; j < 4; ++j) {
                int grow = row0 + wm + mf * 16 + hi * 4 + j;   // (k,m)
                int k = grow >> 8, m = grow & 255;
                int q = q0 + wn + nf * 16 + lr;
                Out[(size_t)(k * 32 + i) * NN + m * 256 + q] = f2b(acc[mf][nf][j]);
            }
}

// ---------------------------------------------------------------------------
// G2P (fused t3+g2): c[(l,u)][(m,q)] = Wt[160x160] @ a[ki][(m,q)]
//     Transpose-on-stage: Bt[pix][ki] (pitch 172 -> conflict-free b64 reads).
//     Wt A-frags loaded from global (L2-hot). 512 thr = 8 waves (2M x 4N).
// ---------------------------------------------------------------------------
__global__ __launch_bounds__(512, 4) void g2p(const unsigned short* __restrict__ Wt,
                                              const unsigned short* __restrict__ a,
                                              unsigned short* __restrict__ c) {
    __shared__ unsigned short Bt[128 * 172];
    int bl = blockIdx.y;
    int n0 = blockIdx.x * 128;
    const unsigned short* asrc = a + (size_t)bl * KC * NN;
    unsigned short* Out = c + (size_t)bl * KC * NN;
    int t = threadIdx.x;

    for (int s = 0; s < 5; ++s) {
        int id = t + s * 512;                 // 0..2559
        int oct = id & 15, ki = id >> 4;      // 16 pixel-octets x 160 ki
        us8 v = *(const us8*)&asrc[(size_t)ki * NN + n0 + oct * 8];
        #pragma unroll
        for (int j = 0; j < 8; ++j)
            Bt[(oct * 8 + j) * 172 + ki] = v[j];
    }
    __syncthreads();

    int w = t >> 6, l = t & 63;
    int mh = w >> 2, nq = w & 3;
    int lr = l & 15, hi = l >> 4;
    f4 acc[5][2];
    for (int mf = 0; mf < 5; ++mf) { acc[mf][0] = (f4)(0.0f); acc[mf][1] = (f4)(0.0f); }

    for (int kk = 0; kk < 5; ++kk) {
        int k0 = kk * 32 + hi * 8;
        bf8 bfr[2];
        #pragma unroll
        for (int nf = 0; nf < 2; ++nf) {
            int pix = (nq * 2 + nf) * 16 + lr;
            s4v lo  = *(const s4v*)&Bt[pix * 172 + k0];
            s4v hi4 = *(const s4v*)&Bt[pix * 172 + k0 + 4];
            bfr[nf] = __builtin_shufflevector(lo, hi4, 0, 1, 2, 3, 4, 5, 6, 7);
        }
        #pragma unroll
        for (int mf = 0; mf < 5; ++mf) {
            int row = mh * 80 + mf * 16 + lr;
            bf8 afr = *(const bf8*)&Wt[(size_t)row * KC + k0];
            acc[mf][0] = __builtin_amdgcn_mfma_f32_16x16x32_bf16(afr, bfr[0], acc[mf][0], 0, 0, 0);
            acc[mf][1] = __builtin_amdgcn_mfma_f32_16x16x32_bf16(afr, bfr[1], acc[mf][1], 0, 0, 0);
        }
    }
    for (int mf = 0; mf < 5; ++mf)
        for (int nf = 0; nf < 2; ++nf)
            for (int j = 0; j < 4; ++j) {
                int row = mh * 80 + mf * 16 + hi * 4 + j;       // (l,u)
                int col = n0 + (nq * 2 + nf) * 16 + lr;         // (m,q)
                Out[(size_t)row * NN + col] = f2b(acc[mf][nf][j]);
            }
}

// ---------------------------------------------------------------------------
// G3: out[b][u][m][n] = sum_{l,q} c[(l*32+u)][(m,q)] * c2T[n][(l,q)]
//     per b: M=8192 (u,m), N=256, K=1280. Same m97-style structure as g1.
// ---------------------------------------------------------------------------
__global__ __launch_bounds__(256, 3) void g3(const unsigned short* __restrict__ c,
                                             const unsigned short* __restrict__ c2T,
                                             float* __restrict__ out, int b_base) {
    __shared__ unsigned short As[128 * 64];
    __shared__ unsigned short Bs[128 * 64];
    int bl = blockIdx.z;
    int b = b_base + bl;
    int R0 = blockIdx.y * 128;             // (u,m); u fixed per block
    int u = R0 >> 8, m0 = R0 & 255;
    int n0 = blockIdx.x * 128;
    const unsigned short* Csrc = c + (size_t)bl * KC * NN;

    int t = threadIdx.x;
    int w = t >> 6, l = t & 63;
    int wm = (w & 1) * 64, wn = (w >> 1) * 64;
    int lr = l & 15, hi = l >> 4;
    int srow = l >> 3;
    int scol = ((l & 7) ^ srow) * 8;

    f4 acc[4][4];
    for (int mf = 0; mf < 4; ++mf) for (int nf = 0; nf < 4; ++nf) acc[mf][nf] = (f4)(0.0f);

    for (int step = 0; step < 20; ++step) {
        int lq = step >> 2, q0 = (step & 3) * 64;
        const unsigned short* Arow0 = Csrc + (size_t)(lq * 32 + u) * NN + (size_t)m0 * 256 + q0;
        const unsigned short* Brow0 = c2T + (size_t)n0 * KQ + step * 64;
        __syncthreads();
        for (int it = 0; it < 4; ++it) {
            int chunk = it * 4 + w;
            int row = chunk * 8 + srow;
            gload16(&Arow0[(size_t)row * 256 + scol], &As[chunk * 512]);
            gload16(&Brow0[(size_t)row * KQ + scol], &Bs[chunk * 512]);
        }
        __syncthreads();
        bf8 af[2][4], bfr[2][4];
        for (int kk = 0; kk < 2; ++kk)
            for (int mf = 0; mf < 4; ++mf) {
                int r = wm + mf * 16 + lr;
                af[kk][mf] = *(const bf8*)&As[r * 64 + (((kk * 4 + hi) ^ (r & 7)) * 8)];
                int rb = wn + mf * 16 + lr;
                bfr[kk][mf] = *(const bf8*)&Bs[rb * 64 + (((kk * 4 + hi) ^ (rb & 7)) * 8)];
            }
        for (int kk = 0; kk < 2; ++kk)
            for (int mf = 0; mf < 4; ++mf)
                for (int nf = 0; nf < 4; ++nf)
                    acc[mf][nf] = __builtin_amdgcn_mfma_f32_16x16x32_bf16(af[kk][mf], bfr[kk][nf], acc[mf][nf], 0, 0, 0);
    }
    for (int mf = 0; mf < 4; ++mf)
        for (int nf = 0; nf < 4; ++nf)
            for (int j = 0; j < 4; ++j) {
                int m = m0 + wm + mf * 16 + hi * 4 + j;
                int n = n0 + wn + nf * 16 + lr;
                out[((size_t)(b * WU + u) * WN + m) * WN + n] = acc[mf][nf][j];
            }
}

// ---------------------------------------------------------------------------
extern "C" void kernel_launch(void* const* d_in, const int* in_sizes, int n_in,
                              void* d_out, int out_size, void* d_ws, size_t ws_size,
                              hipStream_t stream) {
    const float* x     = (const float*)d_in[0];
    const float* cheb1 = (const float*)d_in[1];
    const float* cheb2 = (const float*)d_in[2];
    const float* coefs = (const float*)d_in[3];
    float* out = (float*)d_out;
    unsigned short* ws = (unsigned short*)d_ws;

    size_t off = 0;
    unsigned short* xT  = ws + off; off += (size_t)WB * WC * NN;
    unsigned short* c1T = ws + off; off += (size_t)WK * NN;
    unsigned short* c2T = ws + off; off += (size_t)WN * KQ;
    unsigned short* Wt  = ws + off; off += (size_t)KC * KC;
    size_t fixed_elems = off;
    size_t a1 = (size_t)KC * NN;                 // one batch of a or c

    prep_small<<<1280, 256, 0, stream>>>(cheb1, cheb2, coefs, c1T, c2T, Wt);
    prep_x<<<dim3(4, 4, WB * WC), 256, 0, stream>>>(x, xT);

    size_t avail = ws_size / 2;
    if (avail >= fixed_elems + a1 + (size_t)WB * a1) {
        // full path: single-batch a ping + full c; one big g3
        unsigned short* a_ = ws + fixed_elems;
        unsigned short* c_ = a_ + a1;
        for (int b = 0; b < WB; ++b) {
            g1<<<dim3(2, 10, 32), 256, 0, stream>>>(c1T, xT, a_, b);
            g2p<<<dim3(512, 1), 512, 0, stream>>>(Wt, a_, c_ + (size_t)b * a1);
        }
        g3<<<dim3(2, 64, WB), 256, 0, stream>>>(c_, c2T, out, 0);
    } else {
        size_t per_b = 2 * a1;
        size_t rem = avail > fixed_elems ? avail - fixed_elems : 0;
        int nb = (int)(rem / per_b);
        if (nb < 1) nb = 1;
        if (nb > WB) nb = WB;
        unsigned short* a_ = ws + fixed_elems;
        unsigned short* c_ = a_ + (size_t)nb * a1;
        for (int b0 = 0; b0 < WB; b0 += nb) {
            int cur = (WB - b0 < nb) ? (WB - b0) : nb;
            g1<<<dim3(2, 10, cur * 32), 256, 0, stream>>>(c1T, xT, a_, b0);
            g2p<<<dim3(512, cur), 512, 0, stream>>>(Wt, a_, c_);
            g3<<<dim3(2, 64, cur), 256, 0, stream>>>(c_, c2T, out, b0);
        }
    }
}

// Round 4
// 278.388 us; speedup vs baseline: 1.4518x; 1.1731x over previous
//
#include <hip/hip_runtime.h>
#include <stdint.h>

#define WB 8
#define WC 32
#define WU 32
#define WK 5
#define WN 256
#define NN 65536     // 256*256
#define KC 160       // WK*WC
#define KQ 1280      // WK*WN

typedef __attribute__((ext_vector_type(8))) short bf8;     // 8 x bf16
typedef __attribute__((ext_vector_type(8))) unsigned short us8;
typedef __attribute__((ext_vector_type(4))) float f4;

__device__ __forceinline__ unsigned short f2b(float f) {
    union { float f; uint32_t u; } v; v.f = f;
    uint32_t u = v.u;
    return (unsigned short)((u + 0x7FFFu + ((u >> 16) & 1u)) >> 16);  // RNE
}

// async global->LDS, 16B per lane; lds base must be wave-uniform (m97 pattern)
__device__ __forceinline__ void gload16(const unsigned short* g, unsigned short* l) {
    __builtin_amdgcn_global_load_lds(
        (const __attribute__((address_space(1))) unsigned int*)g,
        (__attribute__((address_space(3))) unsigned int*)l, 16, 0, 0);
}

// ---------------------------------------------------------------------------
// P0: repacks (bf16): c1T[k][m][p], c2T[n][l*256+q], Wt[(l,u)][(k,i)]
// ---------------------------------------------------------------------------
__global__ void prep_small(const float* __restrict__ cheb1,
                           const float* __restrict__ cheb2,
                           const float* __restrict__ coefs,
                           unsigned short* __restrict__ c1T,
                           unsigned short* __restrict__ c2T,
                           unsigned short* __restrict__ Wt) {
    int idx = blockIdx.x * 256 + threadIdx.x;
    if (idx < WK * NN) {            // c1T[k][m][p] = cheb1[k][p][m]
        int k = idx / NN, r = idx % NN, m = r / WN, p = r % WN;
        c1T[idx] = f2b(cheb1[(k * WN + p) * WN + m]);
    }
    if (idx < WN * KQ) {            // c2T[n][lq] = cheb2[lq][n]
        int n = idx / KQ, r = idx % KQ;
        c2T[idx] = f2b(cheb2[r * WN + n]);
    }
    if (idx < KC * KC) {            // Wt[l*32+u][k*32+i] = coefs[k][l][i][u]
        int lu = idx / KC, ki = idx % KC;
        int l = lu >> 5, u = lu & 31, k = ki >> 5, i = ki & 31;
        Wt[idx] = f2b(coefs[((k * WK + l) * WC + i) * WU + u]);
    }
}

// ---------------------------------------------------------------------------
// P1: xT[b][i][q][p] (bf16) = x[b][i][p][q]
// ---------------------------------------------------------------------------
__global__ void prep_x(const float* __restrict__ x, unsigned short* __restrict__ xT) {
    __shared__ unsigned short tile[64][72];
    int bi = blockIdx.z;
    int p0 = blockIdx.y * 64, q0 = blockIdx.x * 64;
    const float* src = x + (size_t)bi * NN;
    unsigned short* dst = xT + (size_t)bi * NN;
    int t = threadIdx.x;
    int c4 = (t & 15) * 4, r0 = t >> 4;
    for (int it = 0; it < 4; ++it) {
        int r = r0 + it * 16;
        float4 v = *reinterpret_cast<const float4*>(&src[(size_t)(p0 + r) * WN + q0 + c4]);
        tile[r][c4 + 0] = f2b(v.x); tile[r][c4 + 1] = f2b(v.y);
        tile[r][c4 + 2] = f2b(v.z); tile[r][c4 + 3] = f2b(v.w);
    }
    __syncthreads();
    for (int it = 0; it < 4; ++it) {
        int q = r0 + it * 16;
        ushort4 o;
        o.x = tile[c4 + 0][q]; o.y = tile[c4 + 1][q];
        o.z = tile[c4 + 2][q]; o.w = tile[c4 + 3][q];
        *reinterpret_cast<ushort4*>(&dst[(size_t)(q0 + q) * WN + p0 + c4]) = o;
    }
}

// ---------------------------------------------------------------------------
// G1: per (b,i): a[(k*32+i)][m][q] = sum_p c1T[(k,m)][p] * xT[b,i][q][p]
//     (round-2 known-good version: row-major a output)
// ---------------------------------------------------------------------------
__global__ __launch_bounds__(256, 3) void g1(const unsigned short* __restrict__ c1T,
                                             const unsigned short* __restrict__ xT,
                                             unsigned short* __restrict__ a, int b_base) {
    __shared__ unsigned short As[128 * 64];
    __shared__ unsigned short Bs[128 * 64];
    int z = blockIdx.z;
    int bl = z >> 5, i = z & 31;
    int row0 = blockIdx.y * 128;            // (k,m) row base
    int q0 = blockIdx.x * 128;
    int b = b_base + bl;
    const unsigned short* Asrc = c1T;                              // pitch 256
    const unsigned short* Bsrc = xT + (size_t)(b * WC + i) * NN;   // pitch 256
    unsigned short* Out = a + (size_t)bl * KC * NN;

    int t = threadIdx.x;
    int w = t >> 6, l = t & 63;
    int wm = (w & 1) * 64, wn = (w >> 1) * 64;
    int lr = l & 15, hi = l >> 4;
    int srow = l >> 3;                       // 0..7 within 8-row chunk
    int scol = ((l & 7) ^ srow) * 8;         // pre-swizzled source col (elems)

    f4 acc[4][4];
    for (int mf = 0; mf < 4; ++mf) for (int nf = 0; nf < 4; ++nf) acc[mf][nf] = (f4)(0.0f);

    for (int p0 = 0; p0 < 256; p0 += 64) {
        __syncthreads();
        for (int it = 0; it < 4; ++it) {
            int chunk = it * 4 + w;
            int row = chunk * 8 + srow;
            gload16(&Asrc[(size_t)(row0 + row) * 256 + p0 + scol], &As[chunk * 512]);
            gload16(&Bsrc[(size_t)(q0 + row) * 256 + p0 + scol], &Bs[chunk * 512]);
        }
        __syncthreads();
        bf8 af[2][4], bfr[2][4];
        for (int kk = 0; kk < 2; ++kk)
            for (int mf = 0; mf < 4; ++mf) {
                int r = wm + mf * 16 + lr;
                af[kk][mf] = *(const bf8*)&As[r * 64 + (((kk * 4 + hi) ^ (r & 7)) * 8)];
                int rb = wn + mf * 16 + lr;
                bfr[kk][mf] = *(const bf8*)&Bs[rb * 64 + (((kk * 4 + hi) ^ (rb & 7)) * 8)];
            }
        for (int kk = 0; kk < 2; ++kk)
            for (int mf = 0; mf < 4; ++mf)
                for (int nf = 0; nf < 4; ++nf)
                    acc[mf][nf] = __builtin_amdgcn_mfma_f32_16x16x32_bf16(af[kk][mf], bfr[kk][nf], acc[mf][nf], 0, 0, 0);
    }
    for (int mf = 0; mf < 4; ++mf)
        for (int nf = 0; nf < 4; ++nf)
            for (int j = 0; j < 4; ++j) {
                int grow = row0 + wm + mf * 16 + hi * 4 + j;   // (k,m)
                int k = grow >> 8, m = grow & 255;
                int q = q0 + wn + nf * 16 + lr;
                Out[(size_t)(k * 32 + i) * NN + m * 256 + q] = f2b(acc[mf][nf][j]);
            }
}

// ---------------------------------------------------------------------------
// G2P (round-2 known-good): c[(l,u)][(m,q)] = Wt[160x160] @ a[ki][(m,q)]
//     Transpose-on-stage Bt[pix][ki] (pitch 172); Wt A-frags from global.
// ---------------------------------------------------------------------------
__global__ __launch_bounds__(512, 4) void g2p(const unsigned short* __restrict__ Wt,
                                              const unsigned short* __restrict__ a,
                                              unsigned short* __restrict__ c) {
    __shared__ unsigned short Bt[128 * 172];
    int bl = blockIdx.y;
    int n0 = blockIdx.x * 128;
    const unsigned short* asrc = a + (size_t)bl * KC * NN;
    unsigned short* Out = c + (size_t)bl * KC * NN;
    int t = threadIdx.x;

    for (int s = 0; s < 5; ++s) {
        int id = t + s * 512;                 // 0..2559
        int oct = id & 15, ki = id >> 4;      // 16 pixel-octets x 160 ki
        us8 v = *(const us8*)&asrc[(size_t)ki * NN + n0 + oct * 8];
        #pragma unroll
        for (int j = 0; j < 8; ++j)
            Bt[(oct * 8 + j) * 172 + ki] = v[j];
    }
    __syncthreads();

    int w = t >> 6, l = t & 63;
    int mh = w >> 2, nq = w & 3;
    int lr = l & 15, hi = l >> 4;
    f4 acc[5][2];
    for (int mf = 0; mf < 5; ++mf) { acc[mf][0] = (f4)(0.0f); acc[mf][1] = (f4)(0.0f); }

    for (int kk = 0; kk < 5; ++kk) {
        int k0 = kk * 32 + hi * 8;
        bf8 bfr[2];
        #pragma unroll
        for (int nf = 0; nf < 2; ++nf) {
            int pix = (nq * 2 + nf) * 16 + lr;
            typedef __attribute__((ext_vector_type(4))) short s4v;
            s4v lo  = *(const s4v*)&Bt[pix * 172 + k0];
            s4v hi4 = *(const s4v*)&Bt[pix * 172 + k0 + 4];
            bfr[nf] = __builtin_shufflevector(lo, hi4, 0, 1, 2, 3, 4, 5, 6, 7);
        }
        #pragma unroll
        for (int mf = 0; mf < 5; ++mf) {
            int row = mh * 80 + mf * 16 + lr;
            bf8 afr = *(const bf8*)&Wt[(size_t)row * KC + k0];
            acc[mf][0] = __builtin_amdgcn_mfma_f32_16x16x32_bf16(afr, bfr[0], acc[mf][0], 0, 0, 0);
            acc[mf][1] = __builtin_amdgcn_mfma_f32_16x16x32_bf16(afr, bfr[1], acc[mf][1], 0, 0, 0);
        }
    }
    for (int mf = 0; mf < 5; ++mf)
        for (int nf = 0; nf < 2; ++nf)
            for (int j = 0; j < 4; ++j) {
                int row = mh * 80 + mf * 16 + hi * 4 + j;       // (l,u)
                int col = n0 + (nq * 2 + nf) * 16 + lr;         // (m,q)
                Out[(size_t)row * NN + col] = f2b(acc[mf][nf][j]);
            }
}

// ---------------------------------------------------------------------------
// G3: out[b][u][m][n] = sum_{l,q} c[(l*32+u)][(m,q)] * c2T[n][(l,q)]
//     Tile 128 x 256 (FULL N): c rows fetched once. 512 thr, 8 waves (2Mx4N).
// ---------------------------------------------------------------------------
__global__ __launch_bounds__(512, 4) void g3(const unsigned short* __restrict__ c,
                                             const unsigned short* __restrict__ c2T,
                                             float* __restrict__ out, int b_base) {
    __shared__ unsigned short As[128 * 64];
    __shared__ unsigned short Bs[256 * 64];
    int bl = blockIdx.y;
    int b = b_base + bl;
    int R0 = blockIdx.x * 128;             // (u,m); u fixed per block
    int u = R0 >> 8, m0 = R0 & 255;
    const unsigned short* Csrc = c + (size_t)bl * KC * NN;

    int t = threadIdx.x;
    int w = t >> 6, l = t & 63;
    int wm = (w >> 2) * 64, wn = (w & 3) * 64;
    int lr = l & 15, hi = l >> 4;
    int srow = l >> 3;
    int scol = ((l & 7) ^ srow) * 8;

    f4 acc[4][4];
    for (int mf = 0; mf < 4; ++mf) for (int nf = 0; nf < 4; ++nf) acc[mf][nf] = (f4)(0.0f);

    for (int step = 0; step < 20; ++step) {
        int lq = step >> 2, q0 = (step & 3) * 64;
        const unsigned short* Arow0 = Csrc + (size_t)(lq * 32 + u) * NN + (size_t)m0 * 256 + q0;
        const unsigned short* Brow0 = c2T + step * 64;
        __syncthreads();
        for (int it = 0; it < 2; ++it) {       // A: 16 chunks of 8 rows
            int chunk = it * 8 + w;
            int row = chunk * 8 + srow;
            gload16(&Arow0[(size_t)row * 256 + scol], &As[chunk * 512]);
        }
        for (int it = 0; it < 4; ++it) {       // B: 32 chunks of 8 rows
            int chunk = it * 8 + w;
            int row = chunk * 8 + srow;
            gload16(&Brow0[(size_t)row * KQ + scol], &Bs[chunk * 512]);
        }
        __syncthreads();
        for (int kk = 0; kk < 2; ++kk) {
            bf8 af[4], bfr[4];
            for (int mf = 0; mf < 4; ++mf) {
                int r = wm + mf * 16 + lr;
                af[mf] = *(const bf8*)&As[r * 64 + (((kk * 4 + hi) ^ (r & 7)) * 8)];
            }
            for (int nf = 0; nf < 4; ++nf) {
                int rb = wn + nf * 16 + lr;
                bfr[nf] = *(const bf8*)&Bs[rb * 64 + (((kk * 4 + hi) ^ (rb & 7)) * 8)];
            }
            for (int mf = 0; mf < 4; ++mf)
                for (int nf = 0; nf < 4; ++nf)
                    acc[mf][nf] = __builtin_amdgcn_mfma_f32_16x16x32_bf16(af[mf], bfr[nf], acc[mf][nf], 0, 0, 0);
        }
    }
    for (int mf = 0; mf < 4; ++mf)
        for (int nf = 0; nf < 4; ++nf)
            for (int j = 0; j < 4; ++j) {
                int m = m0 + wm + mf * 16 + hi * 4 + j;
                int n = wn + nf * 16 + lr;
                out[((size_t)(b * WU + u) * WN + m) * WN + n] = acc[mf][nf][j];
            }
}

// ---------------------------------------------------------------------------
extern "C" void kernel_launch(void* const* d_in, const int* in_sizes, int n_in,
                              void* d_out, int out_size, void* d_ws, size_t ws_size,
                              hipStream_t stream) {
    const float* x     = (const float*)d_in[0];
    const float* cheb1 = (const float*)d_in[1];
    const float* cheb2 = (const float*)d_in[2];
    const float* coefs = (const float*)d_in[3];
    float* out = (float*)d_out;
    unsigned short* ws = (unsigned short*)d_ws;

    size_t off = 0;
    unsigned short* xT  = ws + off; off += (size_t)WB * WC * NN;
    unsigned short* c1T = ws + off; off += (size_t)WK * NN;
    unsigned short* c2T = ws + off; off += (size_t)WN * KQ;
    unsigned short* Wt  = ws + off; off += (size_t)KC * KC;
    size_t fixed_elems = off;
    size_t a1 = (size_t)KC * NN;                 // one batch of a or c (elems)

    prep_small<<<1280, 256, 0, stream>>>(cheb1, cheb2, coefs, c1T, c2T, Wt);
    prep_x<<<dim3(4, 4, WB * WC), 256, 0, stream>>>(x, xT);

    size_t avail = ws_size / 2;
    size_t rem = avail > fixed_elems ? avail - fixed_elems : 0;

    if (rem >= 9 * a1) {
        // full-c path: chunk a by nb batches, single g3 over all 8
        int nb = (int)((rem - 8 * a1) / a1);
        if (nb < 1) nb = 1;
        if (nb > WB) nb = WB;
        unsigned short* a_ = ws + fixed_elems;
        unsigned short* c_ = a_ + (size_t)nb * a1;
        for (int b0 = 0; b0 < WB; b0 += nb) {
            int cur = (WB - b0 < nb) ? (WB - b0) : nb;
            g1<<<dim3(2, 10, cur * 32), 256, 0, stream>>>(c1T, xT, a_, b0);
            g2p<<<dim3(512, cur), 512, 0, stream>>>(Wt, a_, c_ + (size_t)b0 * a1);
        }
        g3<<<dim3(64, WB), 512, 0, stream>>>(c_, c2T, out, 0);
    } else {
        // chunked fallback
        size_t per_b = 2 * a1;
        int nb = (int)(rem / per_b);
        if (nb < 1) nb = 1;
        if (nb > WB) nb = WB;
        unsigned short* a_ = ws + fixed_elems;
        unsigned short* c_ = a_ + (size_t)nb * a1;
        for (int b0 = 0; b0 < WB; b0 += nb) {
            int cur = (WB - b0 < nb) ? (WB - b0) : nb;
            g1<<<dim3(2, 10, cur * 32), 256, 0, stream>>>(c1T, xT, a_, b0);
            g2p<<<dim3(512, cur), 512, 0, stream>>>(Wt, a_, c_);
            g3<<<dim3(64, cur), 512, 0, stream>>>(c_, c2T, out, b0);
        }
    }
}